// Round 2
// baseline (722.152 us; speedup 1.0000x reference)
//
#include <hip/hip_runtime.h>
#include <math.h>

#define B_      32
#define LIN     32000
#define LOUT    31750
#define NF      80
#define FDIM    251
#define FPB     8       // filters per block
#define TPB     256     // threads per block
#define OPT     4       // outputs per thread (consecutive)
#define PPB     (TPB*OPT)   // 1024 positions per block
#define WSTRIDE 256     // padded filter row stride (floats)
#define NCHUNK  63      // ceil(251/4) chunks of 4 taps (tap 251 zero-padded)

// ---------------- Filter construction ----------------
// One block per filter, 256 threads (one tap each, taps 0..250).
// Double precision so our filter matches the fp32 JAX reference to ~1e-7.
__global__ __launch_bounds__(256) void build_filters(
        const float* __restrict__ nf1, const float* __restrict__ nf2,
        const float* __restrict__ ampl, float* __restrict__ filt) {
    const int f = blockIdx.x;
    const int i = threadIdx.x;
    __shared__ double red[256];

    const double fs = 16000.0;
    double f1n = fabs((double)nf1[f]) + 50.0 / fs;
    double f2n = f1n + fabs((double)nf2[f] - f1n) + 50.0 / fs;
    double f1 = f1n * fs;
    double f2 = f2n * fs;
    double amp = fabs((double)ampl[f]);

    double val = 0.0;
    double bp = -1e300;
    if (i < FDIM) {
        int d = i - 125;                      // center at 125
        if (d == 0) {
            val = amp * (2.0 * f2 - 2.0 * f1);    // sinc(0)=1
        } else {
            double t = fabs((double)d) / fs;      // t_right = j/fs, j=1..125
            double a1 = 2.0 * M_PI * f1 * t;
            double a2 = 2.0 * M_PI * f2 * t;
            val = amp * (2.0 * f2 * (sin(a2) / a2) - 2.0 * f1 * (sin(a1) / a1));
        }
        bp = val;
    }
    red[i] = bp;
    __syncthreads();
    #pragma unroll
    for (int s = 128; s > 0; s >>= 1) {
        double other = (i < s) ? red[i + s] : -1e300;
        __syncthreads();              // protect read-modify-write
        if (i < s) red[i] = fmax(red[i], other);
        __syncthreads();
    }
    double mx = red[0];

    if (i < FDIM) {
        // window: 0.54 - 0.46*cos(2*pi*n_i/251), n_i = i*251/250 -> cos(2*pi*i/250)
        double win = 0.54 - 0.46 * cos(2.0 * M_PI * (double)i / 250.0);
        filt[f * WSTRIDE + i] = (float)((val / mx) * win);
    } else {
        filt[f * WSTRIDE + i] = 0.0f;   // zero pad taps 251..255
    }
}

// ---------------- Convolution ----------------
// Block: (position tile of 1024) x (8 filters) x (1 batch).
// Thread: 4 consecutive outputs x 8 filters = 32 fp32 accumulators.
// Taps processed 4 at a time with a sliding 8-register window:
//   per chunk: 8x b128 filter loads (wave-uniform broadcast) + 1x b128 x load
//   vs 128 v_fmac  -> FMA-throughput-bound.
__global__ __launch_bounds__(TPB) void sinc_conv(
        const float* __restrict__ x, const float* __restrict__ filt,
        float* __restrict__ out) {
    __shared__ __align__(16) float sx[PPB + 256];           // 1280 floats
    __shared__ __align__(16) float sw[FPB][WSTRIDE];        // 8 KiB

    const int tile = blockIdx.x;   // 0..31
    const int fg   = blockIdx.y;   // 0..9
    const int b    = blockIdx.z;   // 0..31
    const int tid  = threadIdx.x;

    // --- stage filters: 8*256 = 2048 floats = 512 float4 ---
    {
        const float4* src = (const float4*)(filt + (size_t)fg * FPB * WSTRIDE);
        float4* dst = (float4*)(&sw[0][0]);
        dst[tid]        = src[tid];
        dst[tid + TPB]  = src[tid + TPB];
    }
    // --- stage x tile: 1280 floats = 320 float4 (guarded at row end) ---
    {
        const size_t base = (size_t)b * LIN + (size_t)tile * PPB;
        for (int i = tid; i < (PPB + 256) / 4; i += TPB) {
            int e0 = tile * PPB + i * 4;
            float4 v;
            if (e0 + 3 < LIN) {
                v = *(const float4*)(x + base + i * 4);
            } else {
                v.x = (e0 + 0 < LIN) ? x[base + i * 4 + 0] : 0.0f;
                v.y = (e0 + 1 < LIN) ? x[base + i * 4 + 1] : 0.0f;
                v.z = (e0 + 2 < LIN) ? x[base + i * 4 + 2] : 0.0f;
                v.w = (e0 + 3 < LIN) ? x[base + i * 4 + 3] : 0.0f;
            }
            *(float4*)(&sx[i * 4]) = v;
        }
    }
    __syncthreads();

    float acc[FPB][OPT] = {};

    // sliding window regs: x[p0 + 4*ck .. p0 + 4*ck + 7], p0 = 4*tid (tile-local)
    float4 wa = *(const float4*)(&sx[4 * tid]);
    float4 wb = *(const float4*)(&sx[4 * tid + 4]);

    #pragma unroll 1
    for (int ck = 0; ck < NCHUNK; ++ck) {
        float4 wv[FPB];
        #pragma unroll
        for (int j = 0; j < FPB; ++j)
            wv[j] = *(const float4*)(&sw[j][4 * ck]);       // uniform broadcast

        // prefetch next window quad (max idx 4*255+4*62+8+3 = 1279, in bounds)
        float4 nb = *(const float4*)(&sx[4 * tid + 4 * ck + 8]);

        const float u0 = wa.x, u1 = wa.y, u2 = wa.z, u3 = wa.w;
        const float u4 = wb.x, u5 = wb.y, u6 = wb.z;

        #pragma unroll
        for (int j = 0; j < FPB; ++j) {
            const float4 W = wv[j];
            float* a = acc[j];
            a[0] = fmaf(W.x, u0, a[0]); a[0] = fmaf(W.y, u1, a[0]);
            a[0] = fmaf(W.z, u2, a[0]); a[0] = fmaf(W.w, u3, a[0]);
            a[1] = fmaf(W.x, u1, a[1]); a[1] = fmaf(W.y, u2, a[1]);
            a[1] = fmaf(W.z, u3, a[1]); a[1] = fmaf(W.w, u4, a[1]);
            a[2] = fmaf(W.x, u2, a[2]); a[2] = fmaf(W.y, u3, a[2]);
            a[2] = fmaf(W.z, u4, a[2]); a[2] = fmaf(W.w, u5, a[2]);
            a[3] = fmaf(W.x, u3, a[3]); a[3] = fmaf(W.y, u4, a[3]);
            a[3] = fmaf(W.z, u5, a[3]); a[3] = fmaf(W.w, u6, a[3]);
        }
        wa = wb;
        wb = nb;
    }

    // --- store: [B, NF, LOUT]; LOUT is even but not /4 -> float2 stores ---
    const int p0 = tile * PPB + 4 * tid;
    if (p0 < LOUT) {
        #pragma unroll
        for (int j = 0; j < FPB; ++j) {
            const int f = fg * FPB + j;
            float* orow = out + ((size_t)b * NF + f) * LOUT + p0;
            if (p0 + 3 < LOUT) {
                ((float2*)orow)[0] = make_float2(acc[j][0], acc[j][1]);
                ((float2*)orow)[1] = make_float2(acc[j][2], acc[j][3]);
            } else {
                #pragma unroll
                for (int i = 0; i < OPT; ++i)
                    if (p0 + i < LOUT) orow[i] = acc[j][i];
            }
        }
    }
}

extern "C" void kernel_launch(void* const* d_in, const int* in_sizes, int n_in,
                              void* d_out, int out_size, void* d_ws, size_t ws_size,
                              hipStream_t stream) {
    const float* x    = (const float*)d_in[0];
    const float* nf1  = (const float*)d_in[1];
    const float* nf2  = (const float*)d_in[2];
    const float* ampl = (const float*)d_in[3];
    float* out  = (float*)d_out;
    float* filt = (float*)d_ws;          // 80*256*4 = 80 KiB of workspace

    build_filters<<<dim3(NF), dim3(256), 0, stream>>>(nf1, nf2, ampl, filt);

    dim3 grid((LOUT + PPB - 1) / PPB, NF / FPB, B_);   // 32 x 10 x 32 = 10240 blocks
    sinc_conv<<<grid, dim3(TPB), 0, stream>>>(x, filt, out);
}